// Round 4
// baseline (536.206 us; speedup 1.0000x reference)
//
#include <hip/hip_runtime.h>
#include <math.h>

#define LSEQ 512
#define DG 256
#define DB 128
#define NH 8
#define HD 32
#define EPSV 1e-5f
#define LP2 516          // attn logits LDS row stride
#define KPAD 257         // k-chunk LDS row stride (+1 pad: conflict-free lane=row)

typedef __attribute__((ext_vector_type(8))) short bf16x8;
typedef __attribute__((ext_vector_type(4))) float f32x4;

__device__ __forceinline__ unsigned short f2bf(float x) {
    unsigned int u = __float_as_uint(x);
    u += 0x7FFFu + ((u >> 16) & 1u);       // RNE
    return (unsigned short)(u >> 16);
}
__device__ __forceinline__ float bf2f(unsigned short h) {
    return __uint_as_float(((unsigned int)h) << 16);
}

// ---------------------------------------------------------------------------
// Kernel 1: layernorm(x) + Q/K/V/Gate projections. 256 blocks x 256 thr.
// ---------------------------------------------------------------------------
__global__ __launch_bounds__(256) void prep_kernel(
    const float* __restrict__ x, const float* __restrict__ g_gamma,
    const float* __restrict__ g_beta, const float* __restrict__ Wq,
    const float* __restrict__ Wk, const float* __restrict__ Wv,
    const float* __restrict__ Wg, const float* __restrict__ bg,
    float* __restrict__ q_ws, float* __restrict__ k_ws,
    float* __restrict__ v_ws, float* __restrict__ g_ws)
{
    __shared__ float xs[4][DG];
    const int t = threadIdx.x;
    const int wave = t >> 6, lane = t & 63;
    const int row0 = blockIdx.x << 2;

    {   // one wave per row: layernorm over 256
        const int row = row0 + wave;
        const float4 xv = *(const float4*)(x + (size_t)row * DG + lane * 4);
        float s  = xv.x + xv.y + xv.z + xv.w;
        float ss = xv.x*xv.x + xv.y*xv.y + xv.z*xv.z + xv.w*xv.w;
        #pragma unroll
        for (int m = 32; m >= 1; m >>= 1) { s += __shfl_xor(s, m); ss += __shfl_xor(ss, m); }
        const float mean = s * (1.f / DG);
        const float rstd = rsqrtf(ss * (1.f / DG) - mean * mean + EPSV);
        const float4 gg = *(const float4*)(g_gamma + lane * 4);
        const float4 gb = *(const float4*)(g_beta + lane * 4);
        float4 xo;
        xo.x = (xv.x - mean) * rstd * gg.x + gb.x;
        xo.y = (xv.y - mean) * rstd * gg.y + gb.y;
        xo.z = (xv.z - mean) * rstd * gg.z + gb.z;
        xo.w = (xv.w - mean) * rstd * gg.w + gb.w;
        *(float4*)&xs[wave][lane * 4] = xo;
    }
    __syncthreads();

    float aq[4] = {0,0,0,0}, ak[4] = {0,0,0,0}, av[4] = {0,0,0,0}, ag[4] = {0,0,0,0};
    #pragma unroll 4
    for (int c = 0; c < DG; ++c) {
        const float wq = Wq[(size_t)c * DG + t];
        const float wk = Wk[(size_t)c * DG + t];
        const float wv = Wv[(size_t)c * DG + t];
        const float wg = Wg[(size_t)c * DG + t];
        #pragma unroll
        for (int r = 0; r < 4; ++r) {
            const float xr = xs[r][c];
            aq[r] = fmaf(xr, wq, aq[r]);
            ak[r] = fmaf(xr, wk, ak[r]);
            av[r] = fmaf(xr, wv, av[r]);
            ag[r] = fmaf(xr, wg, ag[r]);
        }
    }

    const float scal = 0.17677669529663687f;  // 1/sqrt(32)
    const float bgv = bg[t];
    #pragma unroll
    for (int r = 0; r < 4; ++r) {
        const size_t o = (size_t)(row0 + r) * DG + t;
        q_ws[o] = aq[r];
        k_ws[o] = ak[r] * scal;
        v_ws[o] = av[r];
        g_ws[o] = 1.f / (1.f + __expf(-(ag[r] + bgv)));
    }
}

// ---------------------------------------------------------------------------
// Kernel 2: bias layernorm + @Wb -> pair_ws [b*l, l, 8].  THE HBM streamer.
// (unchanged from round 3 — est. ~50 us, HBM-bound)
// ---------------------------------------------------------------------------
__global__ __launch_bounds__(256) void pairb_kernel(
    const float* __restrict__ bias, const float* __restrict__ b_gamma,
    const float* __restrict__ b_beta, const float* __restrict__ Wb,
    float* __restrict__ pair_ws)
{
    __shared__ float lds[4 * 2 * 2048];      // 64 KB: [wave][buf][16 rows*128]
    const int t = threadIdx.x;
    const int w = t >> 6, l = t & 63;
    const int n = l & 15, quad = l >> 4;
    const int bq = blockIdx.x;

    bf16x8 gwhi[4], gwlo[4];
    float S1 = 0.f, S0 = 0.f;
    #pragma unroll
    for (int ks = 0; ks < 4; ++ks) {
        #pragma unroll
        for (int j = 0; j < 8; ++j) {
            const int c = ks * 32 + quad * 8 + j;
            const float wb = (n < 8) ? Wb[c * 8 + n] : 0.f;
            const float wv = b_gamma[c] * wb;
            S1 += wv;
            S0 += b_beta[c] * wb;
            unsigned short hi = f2bf(wv);
            unsigned short lo = f2bf(wv - bf2f(hi));
            if (n == 8) { hi = 0x3F80; lo = 0; }   // ones column -> row sums
            gwhi[ks][j] = (short)hi;
            gwlo[ks][j] = (short)lo;
        }
    }
    S1 += __shfl_xor(S1, 16); S1 += __shfl_xor(S1, 32);
    S0 += __shfl_xor(S0, 16); S0 += __shfl_xor(S0, 32);

    float* myl = lds + w * 4096;
    const size_t rowbase = (size_t)bq * LSEQ + w * 16;

    auto stage = [&](int tt, int buf) {
        const float* src = bias + (rowbase + (size_t)tt * 64) * DB;
        float* dst = myl + buf * 2048;
        #pragma unroll
        for (int i = 0; i < 8; ++i) {
            __builtin_amdgcn_global_load_lds(
                (const __attribute__((address_space(1))) void*)(src + i * 256 + l * 4),
                (__attribute__((address_space(3))) void*)(dst + i * 256 + l * 4),
                16, 0, 0);
        }
    };

    auto compute = [&](int tt, int buf) {
        const float* d = myl + buf * 2048 + n * 128 + quad * 8;
        f32x4 acc = {0.f, 0.f, 0.f, 0.f};
        float ssq = 0.f;
        #pragma unroll
        for (int ks = 0; ks < 4; ++ks) {
            const float4 x0 = *(const float4*)(d + ks * 32);
            const float4 x1 = *(const float4*)(d + ks * 32 + 4);
            ssq = fmaf(x0.x,x0.x, fmaf(x0.y,x0.y, fmaf(x0.z,x0.z, fmaf(x0.w,x0.w, ssq))));
            ssq = fmaf(x1.x,x1.x, fmaf(x1.y,x1.y, fmaf(x1.z,x1.z, fmaf(x1.w,x1.w, ssq))));
            const float xsv[8] = {x0.x,x0.y,x0.z,x0.w,x1.x,x1.y,x1.z,x1.w};
            bf16x8 ahi, alo;
            #pragma unroll
            for (int j = 0; j < 8; ++j) {
                const unsigned short hi = f2bf(xsv[j]);
                ahi[j] = (short)hi;
                alo[j] = (short)f2bf(xsv[j] - bf2f(hi));
            }
            acc = __builtin_amdgcn_mfma_f32_16x16x32_bf16(ahi, gwhi[ks], acc, 0, 0, 0);
            acc = __builtin_amdgcn_mfma_f32_16x16x32_bf16(alo, gwhi[ks], acc, 0, 0, 0);
            acc = __builtin_amdgcn_mfma_f32_16x16x32_bf16(ahi, gwlo[ks], acc, 0, 0, 0);
        }
        ssq += __shfl_xor(ssq, 16);
        ssq += __shfl_xor(ssq, 32);
        float* pout = pair_ws + (rowbase + (size_t)tt * 64 + quad * 4) * NH + n;
        #pragma unroll
        for (int reg = 0; reg < 4; ++reg) {
            const float sumr = __uint_as_float((unsigned)__builtin_amdgcn_ds_bpermute(
                (quad * 16 + 8) * 4, (int)__float_as_uint(acc[reg])));
            const float ssqr = __uint_as_float((unsigned)__builtin_amdgcn_ds_bpermute(
                (quad * 4 + reg) * 4, (int)__float_as_uint(ssq)));
            const float mean = sumr * (1.f / DB);
            const float var  = ssqr * (1.f / DB) - mean * mean;
            const float rstd = rsqrtf(var + EPSV);
            const float p = rstd * (acc[reg] - mean * S1) + S0;
            if (n < NH) pout[reg * NH] = p;
        }
    };

    stage(0, 0);
    stage(1, 1);
    asm volatile("s_waitcnt vmcnt(8)" ::: "memory");
    compute(0, 0);
    for (int tt = 1; tt < 7; ++tt) {
        stage(tt + 1, (tt + 1) & 1);
        asm volatile("s_waitcnt vmcnt(12)" ::: "memory");
        compute(tt, tt & 1);
    }
    asm volatile("s_waitcnt vmcnt(4)" ::: "memory");
    compute(7, 1);
}

// ---------------------------------------------------------------------------
// Kernel 3: attention. 512 blocks (2 q-rows each) x 512 thr.
// QK from LDS-staged k chunks (global_load_lds, +1-pad rows, wave=head,
// lane=row -> conflict-free). PV shares v loads across both q.
// ---------------------------------------------------------------------------
__global__ __launch_bounds__(512) void attn_kernel(
    const float* __restrict__ pair_ws, const float* __restrict__ Wout,
    const float* __restrict__ bout, const float* __restrict__ q_ws,
    const float* __restrict__ k_ws, const float* __restrict__ v_ws,
    const float* __restrict__ g_ws, float* __restrict__ out)
{
    __shared__ float lg[2 * NH * LP2];     // 33 KB logits [q][h][k]
    __shared__ float ks_lds[64 * KPAD];    // 64.25 KB k chunk, padded rows
    __shared__ float q_s[2 * DG];
    __shared__ float ps[8][2][DG];         // PV partials, 16 KB
    __shared__ float row_s[2 * DG];
    __shared__ float rden[16];

    const int t = threadIdx.x;
    const int w = t >> 6, l = t & 63;
    const int b = blockIdx.x >> 8;
    const int q0 = (blockIdx.x & 255) * 2;

    // ---- Phase 0: stage pair -> lg (transposed), q rows ----
    {
        const float* pbase = pair_ws + ((size_t)(b * LSEQ + q0)) * LSEQ * NH;
        #pragma unroll
        for (int r = 0; r < 4; ++r) {
            const int f = r * 512 + t;            // float4 index in 2 q slices
            const float4 pv = *(const float4*)(pbase + (size_t)f * 4);
            const int q = f >> 10;
            const int o = (f * 4) & 4095;
            const int k = o >> 3, hb = o & 7;     // hb in {0,4}
            float* dst = lg + (q * NH + hb) * LP2 + k;
            dst[0] = pv.x; dst[LP2] = pv.y; dst[2*LP2] = pv.z; dst[3*LP2] = pv.w;
        }
        q_s[t] = q_ws[((size_t)(b * LSEQ + q0)) * DG + t];
    }
    __syncthreads();

    // ---- Phase 1: QK via LDS-staged k chunks. wave w = head w. ----
    {
        // preload this wave's q fragments (broadcast LDS reads)
        float qr0[32], qr1[32];
        #pragma unroll
        for (int j = 0; j < 8; ++j) {
            const float4 a = *(const float4*)&q_s[w * HD + j * 4];
            const float4 c = *(const float4*)&q_s[DG + w * HD + j * 4];
            qr0[j*4+0]=a.x; qr0[j*4+1]=a.y; qr0[j*4+2]=a.z; qr0[j*4+3]=a.w;
            qr1[j*4+0]=c.x; qr1[j*4+1]=c.y; qr1[j*4+2]=c.z; qr1[j*4+3]=c.w;
        }
        const float* kbase = k_ws + (size_t)(b * LSEQ) * DG;

        for (int ch = 0; ch < 8; ++ch) {
            // stage 64 rows: each wave stages rows {w, w+8, ..., w+56}
            #pragma unroll
            for (int i = 0; i < 8; ++i) {
                const int row = i * 8 + w;
                const float* src = kbase + (size_t)(ch * 64 + row) * DG;
                float* dst = ks_lds + row * KPAD;
                __builtin_amdgcn_global_load_lds(
                    (const __attribute__((address_space(1))) void*)(src + l * 4),
                    (__attribute__((address_space(3))) void*)(dst + l * 4),
                    16, 0, 0);
            }
            __syncthreads();   // drains vmcnt -> chunk ready

            const float* kr = ks_lds + l * KPAD + w * HD;
            float a0 = 0.f, a1 = 0.f;
            #pragma unroll
            for (int j = 0; j < 8; ++j) {
                const float4 kv = *(const float4*)(kr + j * 4);
                a0 = fmaf(kv.x, qr0[j*4+0], fmaf(kv.y, qr0[j*4+1],
                     fmaf(kv.z, qr0[j*4+2], fmaf(kv.w, qr0[j*4+3], a0))));
                a1 = fmaf(kv.x, qr1[j*4+0], fmaf(kv.y, qr1[j*4+1],
                     fmaf(kv.z, qr1[j*4+2], fmaf(kv.w, qr1[j*4+3], a1))));
            }
            const int kidx = ch * 64 + l;
            lg[(0 * NH + w) * LP2 + kidx] += a0;
            lg[(1 * NH + w) * LP2 + kidx] += a1;
            __syncthreads();   // protect buffer for next chunk
        }
    }

    // ---- Phase 2: softmax over k per (q,h): 32 lanes per combo ----
    {
        const int qh = t >> 5, l32 = t & 31;
        float* lrow = lg + qh * LP2;
        float mx = -1e30f;
        #pragma unroll
        for (int i = 0; i < 16; ++i) mx = fmaxf(mx, lrow[l32 + i * 32]);
        #pragma unroll
        for (int m = 16; m >= 1; m >>= 1) mx = fmaxf(mx, __shfl_xor(mx, m));
        float s = 0.f;
        #pragma unroll
        for (int i = 0; i < 16; ++i) {
            const int k = l32 + i * 32;
            const float e = __expf(lrow[k] - mx);
            lrow[k] = e;
            s += e;
        }
        #pragma unroll
        for (int m = 16; m >= 1; m >>= 1) s += __shfl_xor(s, m);
        if (l32 == 0) rden[qh] = 1.f / s;
    }
    __syncthreads();

    // ---- Phase 3: PV. thread=(s8 k-slice, c4); v loaded once for both q ----
    {
        const int s8 = t >> 6, c4 = t & 63, h = c4 >> 3;
        const float* vb = v_ws + ((size_t)(b * LSEQ + s8 * 64)) * DG + c4 * 4;
        const float* p0 = lg + (0 * NH + h) * LP2 + s8 * 64;
        const float* p1 = lg + (1 * NH + h) * LP2 + s8 * 64;
        float4 A0 = {0,0,0,0}, A1 = {0,0,0,0};
        #pragma unroll 2
        for (int i = 0; i < 64; i += 4) {
            const float4 pa = *(const float4*)(p0 + i);
            const float4 pb = *(const float4*)(p1 + i);
            #pragma unroll
            for (int r = 0; r < 4; ++r) {
                const float4 vv = *(const float4*)(vb + (size_t)(i + r) * DG);
                const float wa = (r == 0) ? pa.x : (r == 1) ? pa.y : (r == 2) ? pa.z : pa.w;
                const float wb2 = (r == 0) ? pb.x : (r == 1) ? pb.y : (r == 2) ? pb.z : pb.w;
                A0.x = fmaf(wa, vv.x, A0.x);  A0.y = fmaf(wa, vv.y, A0.y);
                A0.z = fmaf(wa, vv.z, A0.z);  A0.w = fmaf(wa, vv.w, A0.w);
                A1.x = fmaf(wb2, vv.x, A1.x); A1.y = fmaf(wb2, vv.y, A1.y);
                A1.z = fmaf(wb2, vv.z, A1.z); A1.w = fmaf(wb2, vv.w, A1.w);
            }
        }
        *(float4*)&ps[s8][0][c4 * 4] = A0;
        *(float4*)&ps[s8][1][c4 * 4] = A1;
    }
    __syncthreads();
    {
        const int q = t >> 8, c = t & 255;
        float a = ps[0][q][c];
        #pragma unroll
        for (int s8 = 1; s8 < 8; ++s8) a += ps[s8][q][c];
        const float sc = rden[q * NH + (c >> 5)];
        const float g = g_ws[((size_t)(b * LSEQ + q0 + q)) * DG + c];
        row_s[q * DG + c] = a * sc * g;
    }
    __syncthreads();

    // ---- Phase 4: row_s @ Wout + bout ----
    {
        const int q = t >> 8, co = t & 255;
        const float* rs = row_s + q * DG;
        const float* wo = Wout + co;
        float a = 0.f;
        #pragma unroll 4
        for (int c = 0; c < DG; ++c)
            a = fmaf(rs[c], wo[(size_t)c * DG], a);
        out[((size_t)(b * LSEQ + q0 + q)) * DG + co] = a + bout[co];
    }
}

extern "C" void kernel_launch(void* const* d_in, const int* in_sizes, int n_in,
                              void* d_out, int out_size, void* d_ws, size_t ws_size,
                              hipStream_t stream)
{
    const float* x       = (const float*)d_in[0];
    const float* bias    = (const float*)d_in[1];
    const float* g_gamma = (const float*)d_in[2];
    const float* g_beta  = (const float*)d_in[3];
    const float* b_gamma = (const float*)d_in[4];
    const float* b_beta  = (const float*)d_in[5];
    const float* Wq      = (const float*)d_in[6];
    const float* Wk      = (const float*)d_in[7];
    const float* Wv      = (const float*)d_in[8];
    const float* Wb      = (const float*)d_in[9];
    const float* Wg      = (const float*)d_in[10];
    const float* bg      = (const float*)d_in[11];
    const float* Wout    = (const float*)d_in[12];
    const float* bout    = (const float*)d_in[13];
    float* out = (float*)d_out;

    float* ws      = (float*)d_ws;
    float* q_ws    = ws;                    // 1 MB each
    float* k_ws    = ws + 262144;
    float* v_ws    = ws + 2 * 262144;
    float* g_ws    = ws + 3 * 262144;
    float* pair_ws = ws + 4 * 262144;       // 16 MB

    hipLaunchKernelGGL(prep_kernel, dim3(256), dim3(256), 0, stream,
                       x, g_gamma, g_beta, Wq, Wk, Wv, Wg, bg,
                       q_ws, k_ws, v_ws, g_ws);
    hipLaunchKernelGGL(pairb_kernel, dim3(1024), dim3(256), 0, stream,
                       bias, b_gamma, b_beta, Wb, pair_ws);
    hipLaunchKernelGGL(attn_kernel, dim3(512), dim3(512), 0, stream,
                       pair_ws, Wout, bout, q_ws, k_ws, v_ws, g_ws, out);
}